// Round 16
// baseline (286.175 us; speedup 1.0000x reference)
//
#include <hip/hip_runtime.h>

// GCN aggregation: out[t] = norm[t] * sum_{e:dst=t} norm[src]*x[src] + EPS*x[t]
// Round 25: two-level radix partition. Session evidence: sortgather ~43-44 us
// is robust (r14/r15/r7 restructures all failed); residual ~97 us of the 140.1
// best is dominated by partition's fragment-scatter (42-84B fragments x 1.25M
// edges into shared bucket arrays -> cross-XCD RFO churn; 61 us visible in r2,
// structurally unchanged since). Fix keeps r11's contiguous-rec reader but
// makes ALL record writes streaming:
//   pass1: LDS-sort 8192-edge blocks by coarse dst-group (NG=ceil(n/8192)),
//          stream ~2.5 KB fragments to rec1[g] regions; pack (s<<13)|(t&8191).
//          srec (src side, 1.25 MB) scattered directly as in r11.
//   pass2: per 4096-record slice of each group: contiguous read, LDS-sort into
//          the group's 32 final buckets, reserve via curD, stream ~1 KB
//          fragments into the EXACT r11 rec layout ((s<<8)|(t&255), capb).
// sortgather/degnorm/yhconv/cleanup = r11 verbatim. 6 launches + 1 memset.
constexpr int D        = 64;
constexpr float EPS    = 0.5f;
constexpr int BKT      = 256;    // nodes per final bucket
constexpr int CAPB_MAX = 4096;
constexpr int GBITS    = 13;     // coarse group = 8192 nodes = 32 buckets
constexpr int GSZ      = 1 << GBITS;
constexpr int NGMAX    = 64;
constexpr int EPB1     = 8192;   // pass1 edges per block
constexpr int SL2      = 4096;   // pass2 records per block
constexpr int PTHREADS = 512;
constexpr int GTHREADS = 1024;   // sortgather block size (16 waves)
constexpr int NTHREADS = 512;    // degnorm block size
constexpr int NBMAX    = 512;    // max final buckets (n <= 131072)
constexpr int MAXOVF   = 65536;

__device__ __forceinline__ unsigned int f2bf(float f) {
    unsigned int u = __float_as_uint(f);
    return (u + 0x7FFFu + ((u >> 16) & 1u)) >> 16;   // RNE to bf16
}
__device__ __forceinline__ float bf2f_lo(unsigned int v) { return __uint_as_float(v << 16); }
__device__ __forceinline__ float bf2f_hi(unsigned int v) { return __uint_as_float(v & 0xFFFF0000u); }

__device__ __forceinline__ int findseg(const int* lo, int nseg, int i) {
    int a = 0, b = nseg;                      // lo[a] <= i < lo[b]
    while (b - a > 1) { int m = (a + b) >> 1; if (i >= lo[m]) a = m; else b = m; }
    return a;
}

// ---------------- main path ----------------

// pass1: count coarse dst-groups + src buckets; LDS-sort records by group and
// stream 2.5 KB fragments to rec1[g*cap1..]; scatter srec bytes directly.
__global__ __launch_bounds__(PTHREADS)
void pass1_kernel(const int* __restrict__ src, const int* __restrict__ dst,
                  int* __restrict__ cur1, int* __restrict__ curS,
                  unsigned int* __restrict__ rec1, unsigned char* __restrict__ srec,
                  int* __restrict__ ovf_cnt, int* __restrict__ ovf,
                  int* __restrict__ sovf_cnt, int* __restrict__ sovf,
                  int E, int NB, int NG, int cap1, int capb) {
    __shared__ unsigned int srt1[EPB1];       // 32 KB
    __shared__ int histG[NGMAX], startG[NGMAX], lo1[NGMAX + 1];
    __shared__ int histS[NBMAX], startS[NBMAX];
    const int base = blockIdx.x * EPB1;
    const int tid  = threadIdx.x;
    const int lane = tid & 63;
    const int cnt  = min(EPB1, E - base);
    const bool full = (cnt == EPB1);

    if (tid < NGMAX) histG[tid] = 0;
    for (int b = tid; b < NB; b += PTHREADS) histS[b] = 0;
    __syncthreads();

    // ---- count ----
    if (full) {
        const int4* s4 = (const int4*)(src + base);
        const int4* d4 = (const int4*)(dst + base);
        #pragma unroll
        for (int k = 0; k < EPB1 / PTHREADS / 4; ++k) {
            int4 sv = s4[tid + k * PTHREADS];
            int4 dv = d4[tid + k * PTHREADS];
            atomicAdd(&histG[dv.x >> GBITS], 1); atomicAdd(&histS[sv.x >> 8], 1);
            atomicAdd(&histG[dv.y >> GBITS], 1); atomicAdd(&histS[sv.y >> 8], 1);
            atomicAdd(&histG[dv.z >> GBITS], 1); atomicAdd(&histS[sv.z >> 8], 1);
            atomicAdd(&histG[dv.w >> GBITS], 1); atomicAdd(&histS[sv.w >> 8], 1);
        }
    } else {
        for (int k = 0; k < EPB1 / PTHREADS; ++k) {
            int e = tid + k * PTHREADS;
            if (e < cnt) {
                atomicAdd(&histG[dst[base + e] >> GBITS], 1);
                atomicAdd(&histS[src[base + e] >> 8], 1);
            }
        }
    }
    __syncthreads();
    // ---- scan lo1 + group reserve (single wave), src reserve ----
    if (tid < 64) {
        int orig = (tid < NG) ? histG[tid] : 0;
        int v = orig;
        #pragma unroll
        for (int off = 1; off < 64; off <<= 1) {
            int t = __shfl_up(v, off);
            if (lane >= off) v += t;
        }
        if (tid < NG) {
            lo1[tid] = v - orig;
            if (tid == NG - 1) lo1[NG] = v;
            startG[tid] = (orig > 0) ? atomicAdd(&cur1[tid], orig) : 0;
            histG[tid] = 0;                    // reuse as rank
        }
    }
    for (int b = tid; b < NB; b += PTHREADS) {
        int c2 = histS[b];
        startS[b] = (c2 > 0) ? atomicAdd(&curS[b], c2) : 0;
        histS[b] = 0;
    }
    __syncthreads();
    // ---- place: srt1 LDS (by group) + srec global scatter ----
    if (full) {
        const int4* s4 = (const int4*)(src + base);
        const int4* d4 = (const int4*)(dst + base);
        #pragma unroll
        for (int k = 0; k < EPB1 / PTHREADS / 4; ++k) {
            int4 sv = s4[tid + k * PTHREADS];
            int4 dv = d4[tid + k * PTHREADS];
            int ss[4] = {sv.x, sv.y, sv.z, sv.w};
            int tt[4] = {dv.x, dv.y, dv.z, dv.w};
            #pragma unroll
            for (int j = 0; j < 4; ++j) {
                int s = ss[j], t = tt[j];
                int g = t >> GBITS;
                int r = atomicAdd(&histG[g], 1);
                srt1[lo1[g] + r] = ((unsigned int)s << GBITS) | (unsigned int)(t & (GSZ - 1));
                int bS = s >> 8;
                int r2 = atomicAdd(&histS[bS], 1);
                int p2 = startS[bS] + r2;
                if (p2 < capb) {
                    srec[(size_t)bS * capb + p2] = (unsigned char)(s & 255);
                } else {
                    int i = atomicAdd(sovf_cnt, 1);
                    if (i < MAXOVF) sovf[i] = s;
                }
            }
        }
    } else {
        for (int k = 0; k < EPB1 / PTHREADS; ++k) {
            int e = tid + k * PTHREADS;
            if (e < cnt) {
                int s = src[base + e], t = dst[base + e];
                int g = t >> GBITS;
                int r = atomicAdd(&histG[g], 1);
                srt1[lo1[g] + r] = ((unsigned int)s << GBITS) | (unsigned int)(t & (GSZ - 1));
                int bS = s >> 8;
                int r2 = atomicAdd(&histS[bS], 1);
                int p2 = startS[bS] + r2;
                if (p2 < capb) {
                    srec[(size_t)bS * capb + p2] = (unsigned char)(s & 255);
                } else {
                    int i = atomicAdd(sovf_cnt, 1);
                    if (i < MAXOVF) sovf[i] = s;
                }
            }
        }
    }
    __syncthreads();
    // ---- stream out: consecutive i in a group -> consecutive dest (coalesced) ----
    for (int i = tid; i < cnt; i += PTHREADS) {
        int g = findseg(lo1, NG, i);
        int d = startG[g] + (i - lo1[g]);
        unsigned int v = srt1[i];
        if (d < cap1) {
            rec1[(size_t)g * cap1 + d] = v;
        } else {                               // statistically never (13-sigma slack)
            int s = (int)(v >> GBITS);
            int t = (g << GBITS) | (int)(v & (GSZ - 1));
            int i2 = atomicAdd(ovf_cnt, 1);
            if (i2 < MAXOVF) { ovf[2 * i2] = s; ovf[2 * i2 + 1] = t; }
        }
    }
}

// pass2: per (group, slice): contiguous read of 4096 rec1 records, LDS-sort
// into the group's 32 final buckets, reserve via curD, stream ~1 KB fragments
// into the final rec layout ((s<<8)|(t&255), per-bucket capb regions).
__global__ __launch_bounds__(PTHREADS)
void pass2_kernel(const unsigned int* __restrict__ rec1, const int* __restrict__ cur1,
                  int* __restrict__ curD, unsigned int* __restrict__ rec,
                  int* __restrict__ ovf_cnt, int* __restrict__ ovf,
                  int NG, int SPG, int cap1, int capb) {
    __shared__ unsigned int srt[SL2];          // 16 KB
    __shared__ int hist32[32], start32[32], lo32[33];
    const int g   = blockIdx.x / SPG;
    const int sl  = blockIdx.x % SPG;
    const int tid = threadIdx.x;
    const int lane = tid & 63;
    int gcnt = cur1[g];
    if (gcnt > cap1) gcnt = cap1;
    const int base = sl * SL2;
    const int cnt  = min(SL2, gcnt - base);
    if (cnt <= 0) return;
    const unsigned int* in = rec1 + (size_t)g * cap1 + base;

    if (tid < 32) hist32[tid] = 0;
    __syncthreads();
    for (int i = tid; i < cnt; i += PTHREADS)
        atomicAdd(&hist32[(in[i] & (GSZ - 1)) >> 8], 1);
    __syncthreads();
    if (tid < 32) {
        int orig = hist32[tid];
        int v = orig;
        #pragma unroll
        for (int off = 1; off < 32; off <<= 1) {
            int t = __shfl_up(v, off);
            if (lane >= off) v += t;
        }
        lo32[tid] = v - orig;
        if (tid == 31) lo32[32] = v;
        start32[tid] = (orig > 0) ? atomicAdd(&curD[g * 32 + tid], orig) : 0;
        hist32[tid] = 0;                       // reuse as rank
    }
    __syncthreads();
    for (int i = tid; i < cnt; i += PTHREADS) {
        unsigned int v = in[i];
        int bg = (int)((v & (GSZ - 1)) >> 8);
        int r  = atomicAdd(&hist32[bg], 1);
        srt[lo32[bg] + r] = ((v >> GBITS) << 8) | (v & 255u);   // (s<<8)|(t&255)
    }
    __syncthreads();
    for (int i = tid; i < cnt; i += PTHREADS) {
        int bg = findseg(lo32, 32, i);
        int d  = start32[bg] + (i - lo32[bg]);
        unsigned int v = srt[i];
        if (d < capb) {
            rec[(size_t)(g * 32 + bg) * capb + d] = v;
        } else {
            int s = (int)(v >> 8);
            int t = (g << GBITS) | (bg << 8) | (int)(v & 255u);
            int i2 = atomicAdd(ovf_cnt, 1);
            if (i2 < MAXOVF) { ovf[2 * i2] = s; ovf[2 * i2 + 1] = t; }
        }
    }
}

// Per-bucket out-degree histogram from CONTIGUOUS srec[b*capb..] -> norm[].
__global__ __launch_bounds__(NTHREADS)
void degnorm_kernel(const unsigned char* __restrict__ srec, const int* __restrict__ curS,
                    const int* __restrict__ sovf_cnt, const int* __restrict__ sovf,
                    float* __restrict__ norm, int n, int capb) {
    const int b   = blockIdx.x;
    const int tid = threadIdx.x;
    __shared__ int hist[BKT];
    if (tid < BKT) hist[tid] = 0;
    __syncthreads();
    int cnt = curS[b];
    if (cnt > capb) cnt = capb;
    const unsigned int* s4 = (const unsigned int*)(srec + (size_t)b * capb);  // capb % 4 == 0
    int nw = cnt >> 2;
    for (int i = tid; i < nw; i += NTHREADS) { // word-wise coalesced
        unsigned int w = s4[i];
        atomicAdd(&hist[w & 255u], 1);
        atomicAdd(&hist[(w >> 8) & 255u], 1);
        atomicAdd(&hist[(w >> 16) & 255u], 1);
        atomicAdd(&hist[w >> 24], 1);
    }
    for (int i = (nw << 2) + tid; i < cnt; i += NTHREADS)
        atomicAdd(&hist[srec[(size_t)b * capb + i]], 1);
    int oc = *sovf_cnt;                        // expected 0
    if (oc > 0) {
        if (oc > MAXOVF) oc = MAXOVF;
        for (int i = tid; i < oc; i += NTHREADS) {
            int s = sovf[i];
            if ((s >> 8) == b) atomicAdd(&hist[s & 255], 1);
        }
    }
    __syncthreads();
    if (tid < BKT) {
        int node = b * BKT + tid;
        if (node < n) norm[node] = rsqrtf(fmaxf((float)hist[tid], 1.0f));
    }
}

// Pure streaming: yh = bf16(norm * x). Grid-strided, full HBM bandwidth.
__global__ __launch_bounds__(256)
void yhconv_kernel(const float2* __restrict__ x2, const float* __restrict__ norm,
                   unsigned int* __restrict__ yh, int total) {
    int stride = gridDim.x * 256;
    for (int i = blockIdx.x * 256 + threadIdx.x; i < total; i += stride) {
        float2 v = x2[i];
        float nm = norm[i >> 5];               // 32 float2 per node; broadcast load
        yh[i] = f2bf(v.x * nm) | (f2bf(v.y * nm) << 16);
    }
}

// One block per bucket (1024 threads = 16 waves, ~39 KB LDS). CONTIGUOUS read
// of the bucket's records, LDS counting sort to per-node src lists (shfl scan,
// 2 barriers), then gather yh rows: 8 nodes/wave (8 lanes x uint4 = 128B row),
// 8-deep unroll for MLP. (r11 verbatim)
__global__ __launch_bounds__(GTHREADS)
void sortgather_kernel(const unsigned int* __restrict__ rec, const int* __restrict__ curD,
                       const float* __restrict__ norm, const uint4* __restrict__ yr4,
                       const float4* __restrict__ x4, float4* __restrict__ out4,
                       int n, int capb) {
    __shared__ unsigned int recs[CAPB_MAX];   // 16 KB
    __shared__ unsigned int srcs[CAPB_MAX];   // 16 KB
    __shared__ int hist[BKT];                 // per-node in-count (pristine after scan)
    __shared__ int rankb[BKT];
    __shared__ int rsL[BKT];                  // per-node exclusive start (pristine)
    __shared__ float nrmL[BKT];               // per-node dst norm
    __shared__ unsigned int wsums[GTHREADS / 64];
    const int b   = blockIdx.x;
    const int tid = threadIdx.x;
    const int lane = tid & 63;
    const int wid  = tid >> 6;

    int cnt = curD[b];
    if (cnt > capb) cnt = capb;
    for (int i = tid; i < cnt; i += GTHREADS) recs[i] = rec[(size_t)b * capb + i];
    if (tid < BKT) {
        hist[tid] = 0;
        int node = b * BKT + tid;
        nrmL[tid] = (node < n) ? norm[node] : 1.0f;
    }
    __syncthreads();
    for (int i = tid; i < cnt; i += GTHREADS) atomicAdd(&hist[recs[i] & (BKT - 1)], 1);
    __syncthreads();
    // ---- per-wave shfl inclusive scan over hist[0..BKT) (threads 0..255) ----
    {
        int v = (tid < BKT) ? hist[tid] : 0;
        #pragma unroll
        for (int off = 1; off < 64; off <<= 1) {
            int t = __shfl_up(v, off);
            if (lane >= off) v += t;
        }
        if (tid < BKT && lane == 63) wsums[wid] = (unsigned int)v;
        __syncthreads();
        if (tid < BKT) {
            int add = 0;
            #pragma unroll
            for (int w = 0; w < BKT / 64; ++w)
                if (w < wid) add += (int)wsums[w];
            int excl = v + add - hist[tid];
            rankb[tid] = excl;
            rsL[tid]   = excl;
        }
    }
    __syncthreads();
    for (int i = tid; i < cnt; i += GTHREADS) {
        unsigned int v = recs[i];
        int pos = atomicAdd(&rankb[v & (BKT - 1)], 1);
        srcs[pos] = v >> 8;
    }
    __syncthreads();

    // ---- gather phase: 16 waves x 8 nodes -> 128 nodes/round, 2 rounds ----
    const int fl  = lane & 7;                  // uint4 index within 128B row
    const int oct = lane >> 3;                 // node within 8-node group
    #pragma unroll
    for (int r = 0; r < BKT / 128; ++r) {
        int ln   = r * 128 + wid * 8 + oct;    // local node 0..255
        int node = b * BKT + ln;
        bool valid = node < n;
        int rsl = valid ? rsL[ln]  : 0;
        int cl  = valid ? hist[ln] : 0;
        int m = cl;                            // uniform loop count = wave-max
        m = max(m, __shfl_xor(m, 8));
        m = max(m, __shfl_xor(m, 16));
        m = max(m, __shfl_xor(m, 32));
        float a0 = 0.f, a1 = 0.f, a2 = 0.f, a3 = 0.f;
        float a4 = 0.f, a5 = 0.f, a6 = 0.f, a7 = 0.f;
        for (int k = 0; k < m; k += 8) {
            int sb[8];
            #pragma unroll
            for (int j = 0; j < 8; ++j) {      // 8 LDS reads issue together
                int kj = k + j;
                sb[j] = (kj < cl) ? (int)srcs[rsl + kj] : -1;
            }
            #pragma unroll
            for (int j = 0; j < 8; ++j) {      // 8 row loads in flight
                bool take = sb[j] >= 0;
                int s = take ? sb[j] : 0;      // dummy hits node 0's cached row
                uint4 v = yr4[(size_t)s * 8 + fl];
                if (!take) { v.x = 0u; v.y = 0u; v.z = 0u; v.w = 0u; }
                a0 += bf2f_lo(v.x); a1 += bf2f_hi(v.x);
                a2 += bf2f_lo(v.y); a3 += bf2f_hi(v.y);
                a4 += bf2f_lo(v.z); a5 += bf2f_hi(v.z);
                a6 += bf2f_lo(v.w); a7 += bf2f_hi(v.w);
            }
        }
        if (valid) {
            float nt = nrmL[ln];
            size_t basei = (size_t)node * 16 + fl * 2;
            float4 xv0 = x4[basei], xv1 = x4[basei + 1];
            float4 r0, r1;
            r0.x = a0 * nt + EPS * xv0.x;  r0.y = a1 * nt + EPS * xv0.y;
            r0.z = a2 * nt + EPS * xv0.z;  r0.w = a3 * nt + EPS * xv0.w;
            r1.x = a4 * nt + EPS * xv1.x;  r1.y = a5 * nt + EPS * xv1.y;
            r1.z = a6 * nt + EPS * xv1.z;  r1.w = a7 * nt + EPS * xv1.w;
            out4[basei] = r0;              // coalesced: 32B/lane
            out4[basei + 1] = r1;
        }
    }
}

// rare: overflow edges from any stage (expected 0)
__global__ void cleanup_kernel(const float* __restrict__ x, const float* __restrict__ norm,
                               const int* __restrict__ ovf_cnt, const int* __restrict__ ovf,
                               float* __restrict__ out) {
    int cnt = *ovf_cnt;
    if (cnt > MAXOVF) cnt = MAXOVF;
    long long total = (long long)cnt * D;
    long long stride = (long long)gridDim.x * blockDim.x;
    for (long long i = blockIdx.x * (long long)blockDim.x + threadIdx.x; i < total; i += stride) {
        int e = (int)(i >> 6), d = (int)(i & 63);
        int s = ovf[2 * e], t = ovf[2 * e + 1];
        atomicAdd(&out[(size_t)t * D + d], norm[s] * norm[t] * x[(size_t)s * D + d]);
    }
}

// ---------------- tiny-ws / big-n fallback (round-1 proven) ----------------

__global__ void fb_hist(const int* __restrict__ src, int* __restrict__ deg, int E) {
    int e = blockIdx.x * blockDim.x + threadIdx.x;
    if (e < E) atomicAdd(&deg[src[e]], 1);
}
__global__ void fb_norm(const int* __restrict__ deg, float* __restrict__ norm, int n) {
    int i = blockIdx.x * blockDim.x + threadIdx.x;
    if (i < n) norm[i] = rsqrtf(fmaxf((float)deg[i], 1.0f));
}
__global__ void fb_init_out(const float4* __restrict__ x, float4* __restrict__ out, int n4) {
    int i = blockIdx.x * blockDim.x + threadIdx.x;
    if (i < n4) {
        float4 v = x[i];
        out[i] = make_float4(v.x * EPS, v.y * EPS, v.z * EPS, v.w * EPS);
    }
}
__global__ void fb_scatter(const float* __restrict__ x, const int* __restrict__ src,
                           const int* __restrict__ dst, const float* __restrict__ norm,
                           float* __restrict__ out, int E) {
    long long tid = (long long)blockIdx.x * blockDim.x + threadIdx.x;
    int e = (int)(tid >> 6), d = (int)(tid & 63);
    if (e < E) {
        int s = src[e], t = dst[e];
        atomicAdd(&out[(size_t)t * D + d], norm[s] * norm[t] * x[(size_t)s * D + d]);
    }
}

// ---------------- launcher ----------------

extern "C" void kernel_launch(void* const* d_in, const int* in_sizes, int n_in,
                              void* d_out, int out_size, void* d_ws, size_t ws_size,
                              hipStream_t stream) {
    const float* x   = (const float*)d_in[0];
    const int*   src = (const int*)d_in[1];
    const int*   dst = (const int*)d_in[2];
    float* out = (float*)d_out;

    const int ND = in_sizes[0];
    const int E  = in_sizes[1];
    const int n  = ND / D;
    const int NB = (n + BKT - 1) / BKT;
    const int NG = (n + GSZ - 1) >> GBITS;
    constexpr int B = 256;
    const int NB64 = (NB + 63) & ~63;
    const int NG64 = 64;

    const int cap1 = (((E + (NG > 0 ? NG : 1) - 1) / (NG > 0 ? NG : 1)) + 4096 + 15) & ~15;
    const int SPG  = (cap1 + SL2 - 1) / SL2;

    int capb = 0;
    for (int c : {4096, 3584}) {               // divisible by 16
        size_t srecB = ((size_t)NB * c + 15) & ~15ull;
        size_t need = (size_t)NG * cap1 * 4             // rec1 (coarse u32)
                    + (size_t)NB * c * 4                // rec (final u32)
                    + srecB                             // srec (u8)
                    + (size_t)ND * 2                    // yh
                    + (size_t)n * 4                     // norm
                    + (size_t)(NG64 + 2 * NB64 + 128) * 4
                    + (size_t)3 * MAXOVF * 4;           // ovf + sovf
        if (need <= ws_size) { capb = c; break; }
    }

    if (NB <= NBMAX && NG <= NGMAX && capb > 0 && n < (1 << 19) && E > 0) {
        unsigned int* rec1  = (unsigned int*)d_ws;                        // NG*cap1 u32
        unsigned int* rec   = rec1 + (size_t)NG * cap1;                   // NB*capb u32
        unsigned char* srec = (unsigned char*)(rec + (size_t)NB * capb);  // NB*capb u8
        size_t srecB        = ((size_t)NB * capb + 15) & ~15ull;
        unsigned int* yh    = (unsigned int*)(srec + srecB);              // ND/2 u32
        float* norm         = (float*)(yh + ND / 2);                      // n
        int* cur1           = (int*)(norm + n);                           // NG64
        int* curD           = cur1 + NG64;                                // NB64
        int* curS           = curD + NB64;                                // NB64
        int* ovf_cnt        = curS + NB64;                                // 64
        int* sovf_cnt       = ovf_cnt + 64;                               // 64
        int* ovf            = sovf_cnt + 64;                              // 2*MAXOVF
        int* sovf           = ovf + 2 * MAXOVF;                           // MAXOVF

        // cur1 + curD + curS + ovf_cnt + sovf_cnt zeroed in one DMA memset
        hipMemsetAsync(cur1, 0, (size_t)(NG64 + 2 * NB64 + 128) * 4, stream);
        pass1_kernel<<<(E + EPB1 - 1) / EPB1, PTHREADS, 0, stream>>>(src, dst, cur1, curS,
                                                                     rec1, srec, ovf_cnt, ovf,
                                                                     sovf_cnt, sovf,
                                                                     E, NB, NG, cap1, capb);
        pass2_kernel<<<NG * SPG, PTHREADS, 0, stream>>>(rec1, cur1, curD, rec,
                                                        ovf_cnt, ovf, NG, SPG, cap1, capb);
        degnorm_kernel<<<NB, NTHREADS, 0, stream>>>(srec, curS, sovf_cnt, sovf, norm, n, capb);
        int yt = ND / 2;
        int yg = (yt + 255) / 256; if (yg > 2048) yg = 2048;
        yhconv_kernel<<<yg, B, 0, stream>>>((const float2*)x, norm, yh, yt);
        sortgather_kernel<<<NB, GTHREADS, 0, stream>>>(rec, curD, norm, (const uint4*)yh,
                                                       (const float4*)x, (float4*)out, n, capb);
        cleanup_kernel<<<32, B, 0, stream>>>(x, norm, ovf_cnt, ovf, out);
    } else {
        int*   deg  = (int*)d_ws;
        float* norm = (float*)d_ws + n;
        hipMemsetAsync(deg, 0, (size_t)n * sizeof(int), stream);
        fb_hist<<<(E + B - 1) / B, B, 0, stream>>>(src, deg, E);
        fb_norm<<<(n + B - 1) / B, B, 0, stream>>>(deg, norm, n);
        fb_init_out<<<(ND / 4 + B - 1) / B, B, 0, stream>>>((const float4*)x, (float4*)out, ND / 4);
        long long total = (long long)E * D;
        fb_scatter<<<(int)((total + B - 1) / B), B, 0, stream>>>(x, src, dst, norm, out, E);
    }
}

// Round 17
// 152.139 us; speedup vs baseline: 1.8810x; 1.8810x over previous
//
#include <hip/hip_runtime.h>

// GCN aggregation: out[t] = norm[t] * sum_{e:dst=t} norm[src]*x[src] + EPS*x[t]
// Round 26 = round 25 with the cap1 capacity bug fixed. r25's 286 us was NOT
// the radix structure: cap1 = E/NG + 4096 undersized full coarse groups
// (expected load = E*GSZ/n = 102,400 > 100,250) -> ~25K overflow edges ->
// cleanup_kernel ran 133 us of scattered atomics (visible in counters).
// Fix: cap1 = min(E, E*GSZ/n + 4096) (13-sigma slack, sigma~307).
//   pass1: LDS-sort 8192-edge blocks by coarse dst-group, stream ~2.5 KB
//          fragments to rec1[g]; srec byte-scatter as in r11.
//   pass2: contiguous 4096-record slices -> LDS-sort into 32 final buckets ->
//          stream into the exact r11 rec layout.
// sortgather/degnorm/yhconv/cleanup = r11 verbatim. 6 launches + 1 memset.
constexpr int D        = 64;
constexpr float EPS    = 0.5f;
constexpr int BKT      = 256;    // nodes per final bucket
constexpr int CAPB_MAX = 4096;
constexpr int GBITS    = 13;     // coarse group = 8192 nodes = 32 buckets
constexpr int GSZ      = 1 << GBITS;
constexpr int NGMAX    = 64;
constexpr int EPB1     = 8192;   // pass1 edges per block
constexpr int SL2      = 4096;   // pass2 records per block
constexpr int PTHREADS = 512;
constexpr int GTHREADS = 1024;   // sortgather block size (16 waves)
constexpr int NTHREADS = 512;    // degnorm block size
constexpr int NBMAX    = 512;    // max final buckets (n <= 131072)
constexpr int MAXOVF   = 65536;

__device__ __forceinline__ unsigned int f2bf(float f) {
    unsigned int u = __float_as_uint(f);
    return (u + 0x7FFFu + ((u >> 16) & 1u)) >> 16;   // RNE to bf16
}
__device__ __forceinline__ float bf2f_lo(unsigned int v) { return __uint_as_float(v << 16); }
__device__ __forceinline__ float bf2f_hi(unsigned int v) { return __uint_as_float(v & 0xFFFF0000u); }

__device__ __forceinline__ int findseg(const int* lo, int nseg, int i) {
    int a = 0, b = nseg;                      // lo[a] <= i < lo[b]
    while (b - a > 1) { int m = (a + b) >> 1; if (i >= lo[m]) a = m; else b = m; }
    return a;
}

// ---------------- main path ----------------

// pass1: count coarse dst-groups + src buckets; LDS-sort records by group and
// stream 2.5 KB fragments to rec1[g*cap1..]; scatter srec bytes directly.
__global__ __launch_bounds__(PTHREADS)
void pass1_kernel(const int* __restrict__ src, const int* __restrict__ dst,
                  int* __restrict__ cur1, int* __restrict__ curS,
                  unsigned int* __restrict__ rec1, unsigned char* __restrict__ srec,
                  int* __restrict__ ovf_cnt, int* __restrict__ ovf,
                  int* __restrict__ sovf_cnt, int* __restrict__ sovf,
                  int E, int NB, int NG, int cap1, int capb) {
    __shared__ unsigned int srt1[EPB1];       // 32 KB
    __shared__ int histG[NGMAX], startG[NGMAX], lo1[NGMAX + 1];
    __shared__ int histS[NBMAX], startS[NBMAX];
    const int base = blockIdx.x * EPB1;
    const int tid  = threadIdx.x;
    const int lane = tid & 63;
    const int cnt  = min(EPB1, E - base);
    const bool full = (cnt == EPB1);

    if (tid < NGMAX) histG[tid] = 0;
    for (int b = tid; b < NB; b += PTHREADS) histS[b] = 0;
    __syncthreads();

    // ---- count ----
    if (full) {
        const int4* s4 = (const int4*)(src + base);
        const int4* d4 = (const int4*)(dst + base);
        #pragma unroll
        for (int k = 0; k < EPB1 / PTHREADS / 4; ++k) {
            int4 sv = s4[tid + k * PTHREADS];
            int4 dv = d4[tid + k * PTHREADS];
            atomicAdd(&histG[dv.x >> GBITS], 1); atomicAdd(&histS[sv.x >> 8], 1);
            atomicAdd(&histG[dv.y >> GBITS], 1); atomicAdd(&histS[sv.y >> 8], 1);
            atomicAdd(&histG[dv.z >> GBITS], 1); atomicAdd(&histS[sv.z >> 8], 1);
            atomicAdd(&histG[dv.w >> GBITS], 1); atomicAdd(&histS[sv.w >> 8], 1);
        }
    } else {
        for (int k = 0; k < EPB1 / PTHREADS; ++k) {
            int e = tid + k * PTHREADS;
            if (e < cnt) {
                atomicAdd(&histG[dst[base + e] >> GBITS], 1);
                atomicAdd(&histS[src[base + e] >> 8], 1);
            }
        }
    }
    __syncthreads();
    // ---- scan lo1 + group reserve (single wave), src reserve ----
    if (tid < 64) {
        int orig = (tid < NG) ? histG[tid] : 0;
        int v = orig;
        #pragma unroll
        for (int off = 1; off < 64; off <<= 1) {
            int t = __shfl_up(v, off);
            if (lane >= off) v += t;
        }
        if (tid < NG) {
            lo1[tid] = v - orig;
            if (tid == NG - 1) lo1[NG] = v;
            startG[tid] = (orig > 0) ? atomicAdd(&cur1[tid], orig) : 0;
            histG[tid] = 0;                    // reuse as rank
        }
    }
    for (int b = tid; b < NB; b += PTHREADS) {
        int c2 = histS[b];
        startS[b] = (c2 > 0) ? atomicAdd(&curS[b], c2) : 0;
        histS[b] = 0;
    }
    __syncthreads();
    // ---- place: srt1 LDS (by group) + srec global scatter ----
    if (full) {
        const int4* s4 = (const int4*)(src + base);
        const int4* d4 = (const int4*)(dst + base);
        #pragma unroll
        for (int k = 0; k < EPB1 / PTHREADS / 4; ++k) {
            int4 sv = s4[tid + k * PTHREADS];
            int4 dv = d4[tid + k * PTHREADS];
            int ss[4] = {sv.x, sv.y, sv.z, sv.w};
            int tt[4] = {dv.x, dv.y, dv.z, dv.w};
            #pragma unroll
            for (int j = 0; j < 4; ++j) {
                int s = ss[j], t = tt[j];
                int g = t >> GBITS;
                int r = atomicAdd(&histG[g], 1);
                srt1[lo1[g] + r] = ((unsigned int)s << GBITS) | (unsigned int)(t & (GSZ - 1));
                int bS = s >> 8;
                int r2 = atomicAdd(&histS[bS], 1);
                int p2 = startS[bS] + r2;
                if (p2 < capb) {
                    srec[(size_t)bS * capb + p2] = (unsigned char)(s & 255);
                } else {
                    int i = atomicAdd(sovf_cnt, 1);
                    if (i < MAXOVF) sovf[i] = s;
                }
            }
        }
    } else {
        for (int k = 0; k < EPB1 / PTHREADS; ++k) {
            int e = tid + k * PTHREADS;
            if (e < cnt) {
                int s = src[base + e], t = dst[base + e];
                int g = t >> GBITS;
                int r = atomicAdd(&histG[g], 1);
                srt1[lo1[g] + r] = ((unsigned int)s << GBITS) | (unsigned int)(t & (GSZ - 1));
                int bS = s >> 8;
                int r2 = atomicAdd(&histS[bS], 1);
                int p2 = startS[bS] + r2;
                if (p2 < capb) {
                    srec[(size_t)bS * capb + p2] = (unsigned char)(s & 255);
                } else {
                    int i = atomicAdd(sovf_cnt, 1);
                    if (i < MAXOVF) sovf[i] = s;
                }
            }
        }
    }
    __syncthreads();
    // ---- stream out: consecutive i in a group -> consecutive dest (coalesced) ----
    for (int i = tid; i < cnt; i += PTHREADS) {
        int g = findseg(lo1, NG, i);
        int d = startG[g] + (i - lo1[g]);
        unsigned int v = srt1[i];
        if (d < cap1) {
            rec1[(size_t)g * cap1 + d] = v;
        } else {                               // 13-sigma slack: statistically never
            int s = (int)(v >> GBITS);
            int t = (g << GBITS) | (int)(v & (GSZ - 1));
            int i2 = atomicAdd(ovf_cnt, 1);
            if (i2 < MAXOVF) { ovf[2 * i2] = s; ovf[2 * i2 + 1] = t; }
        }
    }
}

// pass2: per (group, slice): contiguous read of 4096 rec1 records, LDS-sort
// into the group's 32 final buckets, reserve via curD, stream ~1 KB fragments
// into the final rec layout ((s<<8)|(t&255), per-bucket capb regions).
__global__ __launch_bounds__(PTHREADS)
void pass2_kernel(const unsigned int* __restrict__ rec1, const int* __restrict__ cur1,
                  int* __restrict__ curD, unsigned int* __restrict__ rec,
                  int* __restrict__ ovf_cnt, int* __restrict__ ovf,
                  int NG, int SPG, int cap1, int capb) {
    __shared__ unsigned int srt[SL2];          // 16 KB
    __shared__ int hist32[32], start32[32], lo32[33];
    const int g   = blockIdx.x / SPG;
    const int sl  = blockIdx.x % SPG;
    const int tid = threadIdx.x;
    const int lane = tid & 63;
    int gcnt = cur1[g];
    if (gcnt > cap1) gcnt = cap1;
    const int base = sl * SL2;
    const int cnt  = min(SL2, gcnt - base);
    if (cnt <= 0) return;
    const unsigned int* in = rec1 + (size_t)g * cap1 + base;

    if (tid < 32) hist32[tid] = 0;
    __syncthreads();
    for (int i = tid; i < cnt; i += PTHREADS)
        atomicAdd(&hist32[(in[i] & (GSZ - 1)) >> 8], 1);
    __syncthreads();
    if (tid < 32) {
        int orig = hist32[tid];
        int v = orig;
        #pragma unroll
        for (int off = 1; off < 32; off <<= 1) {
            int t = __shfl_up(v, off);
            if (lane >= off) v += t;
        }
        lo32[tid] = v - orig;
        if (tid == 31) lo32[32] = v;
        start32[tid] = (orig > 0) ? atomicAdd(&curD[g * 32 + tid], orig) : 0;
        hist32[tid] = 0;                       // reuse as rank
    }
    __syncthreads();
    for (int i = tid; i < cnt; i += PTHREADS) {
        unsigned int v = in[i];
        int bg = (int)((v & (GSZ - 1)) >> 8);
        int r  = atomicAdd(&hist32[bg], 1);
        srt[lo32[bg] + r] = ((v >> GBITS) << 8) | (v & 255u);   // (s<<8)|(t&255)
    }
    __syncthreads();
    for (int i = tid; i < cnt; i += PTHREADS) {
        int bg = findseg(lo32, 32, i);
        int d  = start32[bg] + (i - lo32[bg]);
        unsigned int v = srt[i];
        if (d < capb) {
            rec[(size_t)(g * 32 + bg) * capb + d] = v;
        } else {
            int s = (int)(v >> 8);
            int t = (g << GBITS) | (bg << 8) | (int)(v & 255u);
            int i2 = atomicAdd(ovf_cnt, 1);
            if (i2 < MAXOVF) { ovf[2 * i2] = s; ovf[2 * i2 + 1] = t; }
        }
    }
}

// Per-bucket out-degree histogram from CONTIGUOUS srec[b*capb..] -> norm[].
__global__ __launch_bounds__(NTHREADS)
void degnorm_kernel(const unsigned char* __restrict__ srec, const int* __restrict__ curS,
                    const int* __restrict__ sovf_cnt, const int* __restrict__ sovf,
                    float* __restrict__ norm, int n, int capb) {
    const int b   = blockIdx.x;
    const int tid = threadIdx.x;
    __shared__ int hist[BKT];
    if (tid < BKT) hist[tid] = 0;
    __syncthreads();
    int cnt = curS[b];
    if (cnt > capb) cnt = capb;
    const unsigned int* s4 = (const unsigned int*)(srec + (size_t)b * capb);  // capb % 4 == 0
    int nw = cnt >> 2;
    for (int i = tid; i < nw; i += NTHREADS) { // word-wise coalesced
        unsigned int w = s4[i];
        atomicAdd(&hist[w & 255u], 1);
        atomicAdd(&hist[(w >> 8) & 255u], 1);
        atomicAdd(&hist[(w >> 16) & 255u], 1);
        atomicAdd(&hist[w >> 24], 1);
    }
    for (int i = (nw << 2) + tid; i < cnt; i += NTHREADS)
        atomicAdd(&hist[srec[(size_t)b * capb + i]], 1);
    int oc = *sovf_cnt;                        // expected 0
    if (oc > 0) {
        if (oc > MAXOVF) oc = MAXOVF;
        for (int i = tid; i < oc; i += NTHREADS) {
            int s = sovf[i];
            if ((s >> 8) == b) atomicAdd(&hist[s & 255], 1);
        }
    }
    __syncthreads();
    if (tid < BKT) {
        int node = b * BKT + tid;
        if (node < n) norm[node] = rsqrtf(fmaxf((float)hist[tid], 1.0f));
    }
}

// Pure streaming: yh = bf16(norm * x). Grid-strided, full HBM bandwidth.
__global__ __launch_bounds__(256)
void yhconv_kernel(const float2* __restrict__ x2, const float* __restrict__ norm,
                   unsigned int* __restrict__ yh, int total) {
    int stride = gridDim.x * 256;
    for (int i = blockIdx.x * 256 + threadIdx.x; i < total; i += stride) {
        float2 v = x2[i];
        float nm = norm[i >> 5];               // 32 float2 per node; broadcast load
        yh[i] = f2bf(v.x * nm) | (f2bf(v.y * nm) << 16);
    }
}

// One block per bucket (1024 threads = 16 waves, ~39 KB LDS). CONTIGUOUS read
// of the bucket's records, LDS counting sort to per-node src lists (shfl scan,
// 2 barriers), then gather yh rows: 8 nodes/wave (8 lanes x uint4 = 128B row),
// 8-deep unroll for MLP. (r11 verbatim)
__global__ __launch_bounds__(GTHREADS)
void sortgather_kernel(const unsigned int* __restrict__ rec, const int* __restrict__ curD,
                       const float* __restrict__ norm, const uint4* __restrict__ yr4,
                       const float4* __restrict__ x4, float4* __restrict__ out4,
                       int n, int capb) {
    __shared__ unsigned int recs[CAPB_MAX];   // 16 KB
    __shared__ unsigned int srcs[CAPB_MAX];   // 16 KB
    __shared__ int hist[BKT];                 // per-node in-count (pristine after scan)
    __shared__ int rankb[BKT];
    __shared__ int rsL[BKT];                  // per-node exclusive start (pristine)
    __shared__ float nrmL[BKT];               // per-node dst norm
    __shared__ unsigned int wsums[GTHREADS / 64];
    const int b   = blockIdx.x;
    const int tid = threadIdx.x;
    const int lane = tid & 63;
    const int wid  = tid >> 6;

    int cnt = curD[b];
    if (cnt > capb) cnt = capb;
    for (int i = tid; i < cnt; i += GTHREADS) recs[i] = rec[(size_t)b * capb + i];
    if (tid < BKT) {
        hist[tid] = 0;
        int node = b * BKT + tid;
        nrmL[tid] = (node < n) ? norm[node] : 1.0f;
    }
    __syncthreads();
    for (int i = tid; i < cnt; i += GTHREADS) atomicAdd(&hist[recs[i] & (BKT - 1)], 1);
    __syncthreads();
    // ---- per-wave shfl inclusive scan over hist[0..BKT) (threads 0..255) ----
    {
        int v = (tid < BKT) ? hist[tid] : 0;
        #pragma unroll
        for (int off = 1; off < 64; off <<= 1) {
            int t = __shfl_up(v, off);
            if (lane >= off) v += t;
        }
        if (tid < BKT && lane == 63) wsums[wid] = (unsigned int)v;
        __syncthreads();
        if (tid < BKT) {
            int add = 0;
            #pragma unroll
            for (int w = 0; w < BKT / 64; ++w)
                if (w < wid) add += (int)wsums[w];
            int excl = v + add - hist[tid];
            rankb[tid] = excl;
            rsL[tid]   = excl;
        }
    }
    __syncthreads();
    for (int i = tid; i < cnt; i += GTHREADS) {
        unsigned int v = recs[i];
        int pos = atomicAdd(&rankb[v & (BKT - 1)], 1);
        srcs[pos] = v >> 8;
    }
    __syncthreads();

    // ---- gather phase: 16 waves x 8 nodes -> 128 nodes/round, 2 rounds ----
    const int fl  = lane & 7;                  // uint4 index within 128B row
    const int oct = lane >> 3;                 // node within 8-node group
    #pragma unroll
    for (int r = 0; r < BKT / 128; ++r) {
        int ln   = r * 128 + wid * 8 + oct;    // local node 0..255
        int node = b * BKT + ln;
        bool valid = node < n;
        int rsl = valid ? rsL[ln]  : 0;
        int cl  = valid ? hist[ln] : 0;
        int m = cl;                            // uniform loop count = wave-max
        m = max(m, __shfl_xor(m, 8));
        m = max(m, __shfl_xor(m, 16));
        m = max(m, __shfl_xor(m, 32));
        float a0 = 0.f, a1 = 0.f, a2 = 0.f, a3 = 0.f;
        float a4 = 0.f, a5 = 0.f, a6 = 0.f, a7 = 0.f;
        for (int k = 0; k < m; k += 8) {
            int sb[8];
            #pragma unroll
            for (int j = 0; j < 8; ++j) {      // 8 LDS reads issue together
                int kj = k + j;
                sb[j] = (kj < cl) ? (int)srcs[rsl + kj] : -1;
            }
            #pragma unroll
            for (int j = 0; j < 8; ++j) {      // 8 row loads in flight
                bool take = sb[j] >= 0;
                int s = take ? sb[j] : 0;      // dummy hits node 0's cached row
                uint4 v = yr4[(size_t)s * 8 + fl];
                if (!take) { v.x = 0u; v.y = 0u; v.z = 0u; v.w = 0u; }
                a0 += bf2f_lo(v.x); a1 += bf2f_hi(v.x);
                a2 += bf2f_lo(v.y); a3 += bf2f_hi(v.y);
                a4 += bf2f_lo(v.z); a5 += bf2f_hi(v.z);
                a6 += bf2f_lo(v.w); a7 += bf2f_hi(v.w);
            }
        }
        if (valid) {
            float nt = nrmL[ln];
            size_t basei = (size_t)node * 16 + fl * 2;
            float4 xv0 = x4[basei], xv1 = x4[basei + 1];
            float4 r0, r1;
            r0.x = a0 * nt + EPS * xv0.x;  r0.y = a1 * nt + EPS * xv0.y;
            r0.z = a2 * nt + EPS * xv0.z;  r0.w = a3 * nt + EPS * xv0.w;
            r1.x = a4 * nt + EPS * xv1.x;  r1.y = a5 * nt + EPS * xv1.y;
            r1.z = a6 * nt + EPS * xv1.z;  r1.w = a7 * nt + EPS * xv1.w;
            out4[basei] = r0;              // coalesced: 32B/lane
            out4[basei + 1] = r1;
        }
    }
}

// rare: overflow edges from any stage (expected 0)
__global__ void cleanup_kernel(const float* __restrict__ x, const float* __restrict__ norm,
                               const int* __restrict__ ovf_cnt, const int* __restrict__ ovf,
                               float* __restrict__ out) {
    int cnt = *ovf_cnt;
    if (cnt > MAXOVF) cnt = MAXOVF;
    long long total = (long long)cnt * D;
    long long stride = (long long)gridDim.x * blockDim.x;
    for (long long i = blockIdx.x * (long long)blockDim.x + threadIdx.x; i < total; i += stride) {
        int e = (int)(i >> 6), d = (int)(i & 63);
        int s = ovf[2 * e], t = ovf[2 * e + 1];
        atomicAdd(&out[(size_t)t * D + d], norm[s] * norm[t] * x[(size_t)s * D + d]);
    }
}

// ---------------- tiny-ws / big-n fallback (round-1 proven) ----------------

__global__ void fb_hist(const int* __restrict__ src, int* __restrict__ deg, int E) {
    int e = blockIdx.x * blockDim.x + threadIdx.x;
    if (e < E) atomicAdd(&deg[src[e]], 1);
}
__global__ void fb_norm(const int* __restrict__ deg, float* __restrict__ norm, int n) {
    int i = blockIdx.x * blockDim.x + threadIdx.x;
    if (i < n) norm[i] = rsqrtf(fmaxf((float)deg[i], 1.0f));
}
__global__ void fb_init_out(const float4* __restrict__ x, float4* __restrict__ out, int n4) {
    int i = blockIdx.x * blockDim.x + threadIdx.x;
    if (i < n4) {
        float4 v = x[i];
        out[i] = make_float4(v.x * EPS, v.y * EPS, v.z * EPS, v.w * EPS);
    }
}
__global__ void fb_scatter(const float* __restrict__ x, const int* __restrict__ src,
                           const int* __restrict__ dst, const float* __restrict__ norm,
                           float* __restrict__ out, int E) {
    long long tid = (long long)blockIdx.x * blockDim.x + threadIdx.x;
    int e = (int)(tid >> 6), d = (int)(tid & 63);
    if (e < E) {
        int s = src[e], t = dst[e];
        atomicAdd(&out[(size_t)t * D + d], norm[s] * norm[t] * x[(size_t)s * D + d]);
    }
}

// ---------------- launcher ----------------

extern "C" void kernel_launch(void* const* d_in, const int* in_sizes, int n_in,
                              void* d_out, int out_size, void* d_ws, size_t ws_size,
                              hipStream_t stream) {
    const float* x   = (const float*)d_in[0];
    const int*   src = (const int*)d_in[1];
    const int*   dst = (const int*)d_in[2];
    float* out = (float*)d_out;

    const int ND = in_sizes[0];
    const int E  = in_sizes[1];
    const int n  = ND / D;
    const int NB = (n + BKT - 1) / BKT;
    const int NG = (n + GSZ - 1) >> GBITS;
    constexpr int B = 256;
    const int NB64 = (NB + 63) & ~63;
    const int NG64 = 64;

    // per-group expected load = E * GSZ / n (NOT E/NG); 13-sigma slack
    long long expg = (n > 0) ? ((long long)E * GSZ) / n : 0;
    long long c1   = expg + 4096;
    if (c1 > E) c1 = E;
    const int cap1 = (int)((c1 + 15) & ~15ll);
    const int SPG  = (cap1 + SL2 - 1) / SL2;

    int capb = 0;
    for (int c : {4096, 3584}) {               // divisible by 16
        size_t srecB = ((size_t)NB * c + 15) & ~15ull;
        size_t need = (size_t)NG * cap1 * 4             // rec1 (coarse u32)
                    + (size_t)NB * c * 4                // rec (final u32)
                    + srecB                             // srec (u8)
                    + (size_t)ND * 2                    // yh
                    + (size_t)n * 4                     // norm
                    + (size_t)(NG64 + 2 * NB64 + 128) * 4
                    + (size_t)3 * MAXOVF * 4;           // ovf + sovf
        if (need <= ws_size) { capb = c; break; }
    }

    if (NB <= NBMAX && NG <= NGMAX && capb > 0 && n < (1 << 19) && E > 0) {
        unsigned int* rec1  = (unsigned int*)d_ws;                        // NG*cap1 u32
        unsigned int* rec   = rec1 + (size_t)NG * cap1;                   // NB*capb u32
        unsigned char* srec = (unsigned char*)(rec + (size_t)NB * capb);  // NB*capb u8
        size_t srecB        = ((size_t)NB * capb + 15) & ~15ull;
        unsigned int* yh    = (unsigned int*)(srec + srecB);              // ND/2 u32
        float* norm         = (float*)(yh + ND / 2);                      // n
        int* cur1           = (int*)(norm + n);                           // NG64
        int* curD           = cur1 + NG64;                                // NB64
        int* curS           = curD + NB64;                                // NB64
        int* ovf_cnt        = curS + NB64;                                // 64
        int* sovf_cnt       = ovf_cnt + 64;                               // 64
        int* ovf            = sovf_cnt + 64;                              // 2*MAXOVF
        int* sovf           = ovf + 2 * MAXOVF;                           // MAXOVF

        // cur1 + curD + curS + ovf_cnt + sovf_cnt zeroed in one DMA memset
        hipMemsetAsync(cur1, 0, (size_t)(NG64 + 2 * NB64 + 128) * 4, stream);
        pass1_kernel<<<(E + EPB1 - 1) / EPB1, PTHREADS, 0, stream>>>(src, dst, cur1, curS,
                                                                     rec1, srec, ovf_cnt, ovf,
                                                                     sovf_cnt, sovf,
                                                                     E, NB, NG, cap1, capb);
        pass2_kernel<<<NG * SPG, PTHREADS, 0, stream>>>(rec1, cur1, curD, rec,
                                                        ovf_cnt, ovf, NG, SPG, cap1, capb);
        degnorm_kernel<<<NB, NTHREADS, 0, stream>>>(srec, curS, sovf_cnt, sovf, norm, n, capb);
        int yt = ND / 2;
        int yg = (yt + 255) / 256; if (yg > 2048) yg = 2048;
        yhconv_kernel<<<yg, B, 0, stream>>>((const float2*)x, norm, yh, yt);
        sortgather_kernel<<<NB, GTHREADS, 0, stream>>>(rec, curD, norm, (const uint4*)yh,
                                                       (const float4*)x, (float4*)out, n, capb);
        cleanup_kernel<<<32, B, 0, stream>>>(x, norm, ovf_cnt, ovf, out);
    } else {
        int*   deg  = (int*)d_ws;
        float* norm = (float*)d_ws + n;
        hipMemsetAsync(deg, 0, (size_t)n * sizeof(int), stream);
        fb_hist<<<(E + B - 1) / B, B, 0, stream>>>(src, deg, E);
        fb_norm<<<(n + B - 1) / B, B, 0, stream>>>(deg, norm, n);
        fb_init_out<<<(ND / 4 + B - 1) / B, B, 0, stream>>>((const float4*)x, (float4*)out, ND / 4);
        long long total = (long long)E * D;
        fb_scatter<<<(int)((total + B - 1) / B), B, 0, stream>>>(x, src, dst, norm, out, E);
    }
}